// Round 1
// 1080.321 us; speedup vs baseline: 1.0913x; 1.0913x over previous
//
#include <hip/hip_runtime.h>
#include <math.h>

#define B_ 16
#define T_ 4096
#define D_ 1024
#define HID_ 1365
#define NPAD 1408            // 88*16
#define NGRP 88              // NPAD/16
#define N_TOK (B_*T_)
#define RHO_ 0.2f
#define LN_EPS_ 1e-5f
#define SC 1024.0f
#define INV_SC2 (1.0f/(1024.0f*1024.0f))

#define NHT 11               // h-tiles of 128
#define WCHUNKS (NGRP*32*4*16)       // 180224 f16x8 chunks
#define NG16 4096            // 16-token groups
#define ACHUNKS ((size_t)NG16*32*64) // 8388608 f16x8 chunks per buffer

typedef _Float16 f16x8 __attribute__((ext_vector_type(8)));
typedef float f32x4 __attribute__((ext_vector_type(4)));

// async global->LDS, 16B per lane; LDS dest = wave-uniform base + lane*16
__device__ __forceinline__ void gl16(const void* g, void* l) {
  __builtin_amdgcn_global_load_lds(
      (const __attribute__((address_space(1))) unsigned int*)g,
      (__attribute__((address_space(3))) unsigned int*)l, 16, 0, 0);
}

// ---------------- Kernel 1b: split fc1_w (x1024) into hi/lo f16 in MFMA-frag order ---
__global__ __launch_bounds__(256) void wsplit_kernel(
    const float* __restrict__ fc1w, f16x8* __restrict__ whi, f16x8* __restrict__ wlo)
{
  int c = blockIdx.x * 256 + threadIdx.x;
  if (c >= WCHUNKS) return;
  int ln = c & 15, q = (c >> 4) & 3, ks = (c >> 6) & 31, g = c >> 11;
  int n = g * 16 + ln;
  int k = ks * 32 + q * 8;
  f16x8 hi, lo;
#pragma unroll
  for (int j = 0; j < 8; ++j) {
    float v = (n < HID_) ? fc1w[(size_t)n * D_ + k + j] * SC : 0.f;
    _Float16 h = (_Float16)v;
    hi[j] = h;
    lo[j] = (_Float16)(v - (float)h);
  }
  whi[c] = hi;
  wlo[c] = lo;
}

// ---------------- Kernel 1c (fused): LN stats + LN-apply + hi/lo split, frag order ---
// One block per 16-token group; full 16x1024 row tile staged in LDS (attn applied),
// stats computed in-place (bit-identical accumulation order to old ln_stats).
#define FSTR 1028
__global__ __launch_bounds__(256, 2) void lnasplit_kernel(
    const float* __restrict__ emb, const float* __restrict__ attn,
    const float* __restrict__ lnw, const float* __restrict__ lnb,
    f16x8* __restrict__ ahi, f16x8* __restrict__ alo)
{
  __shared__ float tile[16 * FSTR];
  __shared__ float smu[16], srs[16];
  int tid = threadIdx.x;
  int g = blockIdx.x;
  int wave = tid >> 6, lane = tid & 63;
  // load 16 rows x 1024 cols (4096 float4), attn mask applied (attn is 0/1 -> exact)
#pragma unroll
  for (int it = 0; it < 16; ++it) {
    int idx = tid + it * 256;
    int row = idx >> 8, c4 = idx & 255;
    float a = attn[g * 16 + row];
    float4 v = *reinterpret_cast<const float4*>(
        emb + (size_t)(g * 16 + row) * D_ + c4 * 4);
    v.x *= a; v.y *= a; v.z *= a; v.w *= a;
    *reinterpret_cast<float4*>(&tile[row * FSTR + c4 * 4]) = v;
  }
  __syncthreads();
  // stats: wave w handles rows w*4..w*4+3, same per-lane layout as old ln_stats
#pragma unroll
  for (int r4 = 0; r4 < 4; ++r4) {
    int row = wave * 4 + r4;
    float s = 0.f, sq = 0.f;
#pragma unroll
    for (int q = 0; q < 4; ++q) {
      float4 v = *reinterpret_cast<const float4*>(&tile[row * FSTR + lane * 4 + q * 256]);
      s  += v.x + v.y + v.z + v.w;
      sq += v.x * v.x + v.y * v.y + v.z * v.z + v.w * v.w;
    }
#pragma unroll
    for (int off = 32; off > 0; off >>= 1) {
      s  += __shfl_down(s, off, 64);
      sq += __shfl_down(sq, off, 64);
    }
    if (lane == 0) {
      float m = s * (1.f / D_);
      float var = sq * (1.f / D_) - m * m;
      if (var < 0.f) var = 0.f;
      smu[row] = m;
      srs[row] = 1.f / sqrtf(var + LN_EPS_);
    }
  }
  __syncthreads();
  // frag phase: 32 ks-slices x 64 lanes = 2048 items
#pragma unroll
  for (int it = 0; it < 8; ++it) {
    int idx = tid + it * 256;
    int ksl = idx >> 6, l = idx & 63;
    int ln = l & 15, q = l >> 4;
    float rs = srs[ln];
    float nmr = -smu[ln] * rs;
    int colbase = ksl * 32 + q * 8;
    float4 e0 = *reinterpret_cast<const float4*>(&tile[ln * FSTR + colbase]);
    float4 e1 = *reinterpret_cast<const float4*>(&tile[ln * FSTR + colbase + 4]);
    float ev[8] = {e0.x, e0.y, e0.z, e0.w, e1.x, e1.y, e1.z, e1.w};
    f16x8 hi, lo;
#pragma unroll
    for (int j = 0; j < 8; ++j) {
      int kg = colbase + j;
      float wv = lnw[kg], bv = lnb[kg];
      // tile already holds a*emb (a in {0,1}); (ev*a)*rs == ev*(a*rs) exactly
      float y = fmaf(ev[j] * rs, wv, fmaf(nmr, wv, bv)) * SC;
      _Float16 h = (_Float16)y;
      hi[j] = h;
      lo[j] = (_Float16)(y - (float)h);
    }
    size_t c = (size_t)(g * 32 + ksl) * 64 + l;
    ahi[c] = hi;
    alo[c] = lo;
  }
}

// ---------------- Kernel 2 (v5): LDS-staged double-buffered MFMA GEMM ---------------
// Block = 128 tokens x 128 h, 4 waves 2x2 (wave tile 64x64, 4x4 frags, 3 products).
// Per K-step: stage 32 KB of frag chunks via global_load_lds (wave w owns one region:
// 0=Ahi 1=Alo 2=Bhi 3=Blo), double-buffered; one __syncthreads per step (drains vmcnt,
// so the stage issued at step top overlaps this step's ds_read+MFMA).
__global__ __launch_bounds__(256, 2) void mfma_score_v5(
    const f16x8* __restrict__ ahi, const f16x8* __restrict__ alo,
    const f16x8* __restrict__ whi, const f16x8* __restrict__ wlo,
    const float* __restrict__ fc1b, const float* __restrict__ fc2w,
    float* __restrict__ partial)
{
  __shared__ f16x8 sbuf[2][2048];   // 2 x 32KB: [Ahi 0..511 | Alo 512.. | Bhi 1024.. | Blo 1536..]
  __shared__ float red[2][128];
  int tid = threadIdx.x, lane = tid & 63;
  int w = tid >> 6, wrow = w & 1, wcol = w >> 1;
  // XCD-aware swizzle: the 11 ht-blocks of one token-tile stay adjacent per XCD
  int flat = blockIdx.x;            // 0..5631 = 8 XCDs * (64 tb * 11 ht)
  int xcd = flat & 7, j = flat >> 3;
  int tb = xcd * 64 + j / NHT;      // 0..511 token-tiles of 128
  int ht = j % NHT;                 // 0..10
  int g0 = tb * 8;                  // block token-group base (8 groups of 16)
  int hb0 = ht * 8;                 // block h-group base (8 groups of 16)
  int ln16 = lane & 15, quad = lane >> 4;

  // per-wave staging source (chunk-linear frag arrays; per-lane addr = +lane*16B)
  const f16x8* src = (w == 0) ? ahi : (w == 1) ? alo : (w == 2) ? whi : wlo;
  size_t grpbase = (w < 2) ? (size_t)g0 : (size_t)hb0;
  const f16x8* sp = src + grpbase * 32 * 64 + lane;

  // stage K-slice ks of this wave's region into sbuf[buf]
  auto STAGE = [&](int buf, int ks) {
#pragma unroll
    for (int i = 0; i < 8; ++i)
      gl16(sp + (size_t)(i * 32 + ks) * 64, &sbuf[buf][w * 512 + i * 64]);
  };

  STAGE(0, 0);

  f32x4 acc[4][4];
#pragma unroll
  for (int i = 0; i < 4; ++i)
#pragma unroll
    for (int j2 = 0; j2 < 4; ++j2) acc[i][j2] = (f32x4)0.f;

  __syncthreads();   // prologue stage complete (vmcnt drained by barrier)

#pragma unroll 2
  for (int ks = 0; ks < 32; ++ks) {
    int cur = ks & 1;
    if (ks < 31) STAGE(cur ^ 1, ks + 1);   // prefetch next slice over this compute
    f16x8 ah[4], al[4], bh[4], bl[4];
#pragma unroll
    for (int mi = 0; mi < 4; ++mi) {
      ah[mi] = sbuf[cur][(wrow * 4 + mi) * 64 + lane];
      al[mi] = sbuf[cur][512 + (wrow * 4 + mi) * 64 + lane];
    }
#pragma unroll
    for (int nj = 0; nj < 4; ++nj) {
      bh[nj] = sbuf[cur][1024 + (wcol * 4 + nj) * 64 + lane];
      bl[nj] = sbuf[cur][1536 + (wcol * 4 + nj) * 64 + lane];
    }
#pragma unroll
    for (int mi = 0; mi < 4; ++mi)
#pragma unroll
      for (int nj = 0; nj < 4; ++nj) {
        acc[mi][nj] = __builtin_amdgcn_mfma_f32_16x16x32_f16(ah[mi], bh[nj], acc[mi][nj], 0, 0, 0);
        acc[mi][nj] = __builtin_amdgcn_mfma_f32_16x16x32_f16(al[mi], bh[nj], acc[mi][nj], 0, 0, 0);
        acc[mi][nj] = __builtin_amdgcn_mfma_f32_16x16x32_f16(ah[mi], bl[nj], acc[mi][nj], 0, 0, 0);
      }
    __syncthreads();  // drains prefetch vmcnt + protects buffer swap
  }

  // ---- epilogue: bias + exact GELU + fc2 weight, reduce over hidden ----
  int gb0 = hb0 + wcol * 4;
  float s[4][4];
#pragma unroll
  for (int mi = 0; mi < 4; ++mi)
#pragma unroll
    for (int r = 0; r < 4; ++r) s[mi][r] = 0.f;
#pragma unroll
  for (int nj = 0; nj < 4; ++nj) {
    int h = (gb0 + nj) * 16 + ln16;
    float b1 = 0.f, w2 = 0.f;
    if (h < HID_) { b1 = fc1b[h]; w2 = fc2w[h]; }
#pragma unroll
    for (int mi = 0; mi < 4; ++mi)
#pragma unroll
      for (int r = 0; r < 4; ++r) {
        float v = acc[mi][nj][r] * INV_SC2 + b1;
        float gel = 0.5f * v * (1.f + erff(v * 0.70710678118654752440f));
        s[mi][r] = fmaf(gel, w2, s[mi][r]);
      }
  }
#pragma unroll
  for (int mi = 0; mi < 4; ++mi)
#pragma unroll
    for (int r = 0; r < 4; ++r) {
      float v = s[mi][r];
      v += __shfl_xor(v, 1, 64);
      v += __shfl_xor(v, 2, 64);
      v += __shfl_xor(v, 4, 64);
      v += __shfl_xor(v, 8, 64);
      s[mi][r] = v;
    }
  if (ln16 == 0) {
#pragma unroll
    for (int mi = 0; mi < 4; ++mi)
#pragma unroll
      for (int r = 0; r < 4; ++r)
        red[wcol][wrow * 64 + mi * 16 + quad * 4 + r] = s[mi][r];
  }
  __syncthreads();
  if (tid < 128)
    partial[(size_t)ht * N_TOK + tb * 128 + tid] = red[0][tid] + red[1][tid];
}

// ---------------- Kernel 3: slab-reduce + masked softmax + entropy + K + z ----------
__global__ __launch_bounds__(1024) void softmax_kernel(
    const float* __restrict__ partial, const float* __restrict__ fc2b,
    const float* __restrict__ attn,
    float* __restrict__ out_z, float* __restrict__ rowent, float* __restrict__ rowK)
{
  __shared__ float buf[1024];
  int b = blockIdx.x, tid = threadIdx.x;
  const float* arow = attn + b * T_;
  float sv[4], av[4];
  float f2b = fc2b[0];
#pragma unroll
  for (int q = 0; q < 4; ++q) {
    int t = tid + q * 1024;
    av[q] = arow[t];
    float sc = f2b;
#pragma unroll
    for (int p = 0; p < NHT; ++p) sc += partial[(size_t)p * N_TOK + b * T_ + t];
    sv[q] = (av[q] == 0.f) ? -1e9f : sc;
  }
  float m = fmaxf(fmaxf(sv[0], sv[1]), fmaxf(sv[2], sv[3]));
  buf[tid] = m; __syncthreads();
  for (int s = 512; s > 0; s >>= 1) { if (tid < s) buf[tid] = fmaxf(buf[tid], buf[tid + s]); __syncthreads(); }
  m = buf[0]; __syncthreads();
  float e[4]; float es = 0.f, as = 0.f;
#pragma unroll
  for (int q = 0; q < 4; ++q) { e[q] = expf(sv[q] - m); es += e[q]; as += av[q]; }
  buf[tid] = es; __syncthreads();
  for (int s = 512; s > 0; s >>= 1) { if (tid < s) buf[tid] += buf[tid + s]; __syncthreads(); }
  es = buf[0]; __syncthreads();
  buf[tid] = as; __syncthreads();
  for (int s = 512; s > 0; s >>= 1) { if (tid < s) buf[tid] += buf[tid + s]; __syncthreads(); }
  as = buf[0]; __syncthreads();
  float K = fmaxf(1.f, rintf(RHO_ * as));
  float inv = 1.f / es;
  float ent = 0.f;
#pragma unroll
  for (int q = 0; q < 4; ++q) {
    float p = e[q] * inv;
    out_z[b * T_ + tid + q * 1024] = K * p;
    ent -= p * logf(p + 1e-12f);
  }
  buf[tid] = ent; __syncthreads();
  for (int s = 512; s > 0; s >>= 1) { if (tid < s) buf[tid] += buf[tid + s]; __syncthreads(); }
  if (tid == 0) {
    rowent[b] = buf[0] / logf(fmaxf(as, 1.f));
    rowK[b] = K;
  }
}

// ---------------- Kernel 4: per-row exact top-K mask (stable ties) + scalar out ----
__global__ __launch_bounds__(1024) void topk_kernel(
    const float* __restrict__ zall, float* __restrict__ g,
    const float* __restrict__ rowent, const float* __restrict__ rowK,
    float* __restrict__ out_scalar)
{
  __shared__ float sm[T_];
  __shared__ int s_first, s_last;
  int b = blockIdx.x, tid = threadIdx.x;
  const float* zrow = zall + b * T_;
  for (int t = tid; t < T_; t += 1024) sm[t] = zrow[t];
  __syncthreads();
  for (int k = 2; k <= T_; k <<= 1) {
    for (int j = k >> 1; j > 0; j >>= 1) {
      for (int t = tid; t < T_; t += 1024) {
        int ixj = t ^ j;
        if (ixj > t) {
          float a = sm[t], c = sm[ixj];
          bool desc = ((t & k) == 0);
          if (desc ? (a < c) : (a > c)) { sm[t] = c; sm[ixj] = a; }
        }
      }
      __syncthreads();
    }
  }
  int K = (int)rowK[b];
  float thr = sm[K - 1];
  if (tid == 0) { s_first = T_; s_last = -1; }
  __syncthreads();
  for (int t = tid; t < T_; t += 1024) {
    if (sm[t] == thr) { atomicMin(&s_first, t); atomicMax(&s_last, t); }
  }
  __syncthreads();
  int cgt = s_first;
  int eqTotal = s_last - s_first + 1;
  int need = K - cgt;
  float* grow = g + b * T_;
  bool allEq = (eqTotal == need);
  for (int t = tid; t < T_; t += 1024) {
    float zv = zrow[t];
    if (zv > thr) grow[t] = 1.f;
    else if (zv < thr) grow[t] = 0.f;
    else if (allEq) grow[t] = 1.f;
  }
  __syncthreads();
  if (!allEq && tid == 0) {
    int cnt = 0;
    for (int t = 0; t < T_; ++t) {
      float zv = zrow[t];
      if (zv == thr) { grow[t] = (cnt < need) ? 1.f : 0.f; ++cnt; }
    }
  }
  if (b == 0 && tid == 0) {
    float s = 0.f;
    for (int i = 0; i < B_; ++i) s += rowent[i];
    out_scalar[0] = s * (1.f / B_);
  }
}

extern "C" void kernel_launch(void* const* d_in, const int* in_sizes, int n_in,
                              void* d_out, int out_size, void* d_ws, size_t ws_size,
                              hipStream_t stream)
{
  const float* emb  = (const float*)d_in[0];
  const float* attn = (const float*)d_in[1];
  const float* lnw  = (const float*)d_in[2];
  const float* lnb  = (const float*)d_in[3];
  const float* fc1w = (const float*)d_in[4];
  const float* fc1b = (const float*)d_in[5];
  const float* fc2w = (const float*)d_in[6];
  const float* fc2b = (const float*)d_in[7];

  float* out = (float*)d_out;
  float* g  = out;
  float* z  = out + N_TOK;
  float* ns = out + 2 * N_TOK;

  float* mu      = (float*)d_ws;                    // (unused slot, layout kept)
  float* rstd    = mu + N_TOK;                      // (unused slot, layout kept)
  float* partial = rstd + N_TOK;                    // NHT*N_TOK
  float* rowent  = partial + (size_t)NHT * N_TOK;   // 16
  float* rowK    = rowent + 16;                     // 16
  f16x8* whi     = (f16x8*)(rowK + 16);             // WCHUNKS
  f16x8* wlo     = whi + WCHUNKS;
  f16x8* ahi     = wlo + WCHUNKS;                   // ACHUNKS
  f16x8* alo     = ahi + ACHUNKS;

  wsplit_kernel<<<(WCHUNKS + 255) / 256, 256, 0, stream>>>(fc1w, whi, wlo);
  lnasplit_kernel<<<NG16, 256, 0, stream>>>(emb, attn, lnw, lnb, ahi, alo);
  mfma_score_v5<<<8 * 64 * NHT, 256, 0, stream>>>(ahi, alo, whi, wlo, fc1b, fc2w, partial);
  softmax_kernel<<<B_, 1024, 0, stream>>>(partial, fc2b, attn, z, rowent, rowK);
  topk_kernel<<<B_, 1024, 0, stream>>>(z, g, rowent, rowK, ns);
}